// Round 1
// baseline (242.829 us; speedup 1.0000x reference)
//
#include <hip/hip_runtime.h>
#include <hip/hip_bf16.h>

// Problem dims (fixed by reference)
#define NS 256   // n_samples
#define NC 32    // n_channels (== K of the matvec)
#define NL 64    // lookback
#define NA 512   // n_assets
#define NH 32    // hidden

typedef float  f32x4  __attribute__((ext_vector_type(4)));
typedef __bf16 bf16x8 __attribute__((ext_vector_type(8)));

// tanh(x) = (e^{2x}-1)/(e^{2x}+1), via hw exp2/rcp. Clamp keeps t finite.
__device__ __forceinline__ float fast_tanh(float x) {
    float xc = fminf(fmaxf(x, -9.0f), 9.0f);
    // 2*log2(e) = 2.885390081777927
    float t = __builtin_amdgcn_exp2f(xc * 2.885390081777927f);
    return (t - 1.0f) * __builtin_amdgcn_rcpf(t + 1.0f);
}

// out[s,h,a] = (1/64) * sum_l tanh( sum_c x[s,c,l,a]*W[h,c] + bias[h] )
// One wave owns (s, 16-wide a tile). MFMA 16x16x32 bf16: M=h(2 tiles of 16),
// N=a(16), K=c(32, single MFMA).
__global__ __launch_bounds__(256, 4) void tcrnn_kernel(
    const float* __restrict__ x,
    const float* __restrict__ Wih,
    const float* __restrict__ bih,
    const float* __restrict__ bhh,
    float* __restrict__ out)
{
    const int tid   = threadIdx.x;
    const int lane  = tid & 63;
    const int wave  = tid >> 6;          // 0..3
    const int bid   = blockIdx.x;        // 0..2047
    const int s     = bid >> 3;          // 0..255
    const int chunk = bid & 7;           // 8 chunks of 64 assets

    const int n     = lane & 15;         // col (a) within tile / row (h) for A
    const int g     = lane >> 4;         // k-group 0..3
    const int cbase = g * 8;             // this lane's k (=channel) base
    const int a     = chunk * 64 + wave * 16 + n;

    // ---- A fragments: W[h][c], h = t*16 + (lane&15), k = cbase + j ----
    bf16x8 Af[2];
    #pragma unroll
    for (int t = 0; t < 2; ++t) {
        const int h = t * 16 + n;
        const float4 w0 = *reinterpret_cast<const float4*>(Wih + h * NC + cbase);
        const float4 w1 = *reinterpret_cast<const float4*>(Wih + h * NC + cbase + 4);
        Af[t][0] = (__bf16)w0.x; Af[t][1] = (__bf16)w0.y;
        Af[t][2] = (__bf16)w0.z; Af[t][3] = (__bf16)w0.w;
        Af[t][4] = (__bf16)w1.x; Af[t][5] = (__bf16)w1.y;
        Af[t][6] = (__bf16)w1.z; Af[t][7] = (__bf16)w1.w;
    }

    // ---- per-lane output bias: h_out = t*16 + g*4 + r ----
    float bias[8];
    #pragma unroll
    for (int t = 0; t < 2; ++t)
        #pragma unroll
        for (int r = 0; r < 4; ++r) {
            const int h = t * 16 + g * 4 + r;
            bias[t * 4 + r] = bih[h] + bhh[h];
        }

    // x[s][c][l][a] : c-stride = NL*NA, l-stride = NA
    const float* xp = x + ((size_t)s * NC + cbase) * (NL * NA) + a;

    f32x4 acc0 = {0.f, 0.f, 0.f, 0.f};
    f32x4 acc1 = {0.f, 0.f, 0.f, 0.f};
    const f32x4 z = {0.f, 0.f, 0.f, 0.f};

    #pragma unroll 4
    for (int l = 0; l < NL; ++l) {
        const float* p = xp + l * NA;
        bf16x8 B;
        #pragma unroll
        for (int j = 0; j < 8; ++j)
            B[j] = (__bf16)p[(size_t)j * (NL * NA)];

        f32x4 pre0 = __builtin_amdgcn_mfma_f32_16x16x32_bf16(Af[0], B, z, 0, 0, 0);
        f32x4 pre1 = __builtin_amdgcn_mfma_f32_16x16x32_bf16(Af[1], B, z, 0, 0, 0);

        #pragma unroll
        for (int r = 0; r < 4; ++r) {
            acc0[r] += fast_tanh(pre0[r] + bias[r]);
            acc1[r] += fast_tanh(pre1[r] + bias[4 + r]);
        }
    }

    // ---- store: D col = lane&15 (=a), row = g*4 + r (+16 for tile 1) ----
    float* op = out + (size_t)s * (NH * NA) + a;
    #pragma unroll
    for (int r = 0; r < 4; ++r) {
        op[(size_t)(g * 4 + r) * NA]        = acc0[r] * 0.015625f;
        op[(size_t)(16 + g * 4 + r) * NA]   = acc1[r] * 0.015625f;
    }
}

extern "C" void kernel_launch(void* const* d_in, const int* in_sizes, int n_in,
                              void* d_out, int out_size, void* d_ws, size_t ws_size,
                              hipStream_t stream) {
    const float* x    = (const float*)d_in[0];
    const float* Wih  = (const float*)d_in[1];
    // d_in[2] = W_hh: mathematically dead (hx == 0 every step)
    const float* bih  = (const float*)d_in[3];
    const float* bhh  = (const float*)d_in[4];
    float* out = (float*)d_out;

    dim3 grid(NS * 8);   // 256 samples * 8 asset-chunks of 64
    dim3 block(256);
    tcrnn_kernel<<<grid, block, 0, stream>>>(x, Wih, bih, bhh, out);
}

// Round 2
// 215.249 us; speedup vs baseline: 1.1281x; 1.1281x over previous
//
#include <hip/hip_runtime.h>
#include <hip/hip_bf16.h>

// Problem dims (fixed by reference)
#define NS 256   // n_samples
#define NC 32    // n_channels (== K of the matvec)
#define NL 64    // lookback
#define NA 512   // n_assets
#define NH 32    // hidden

typedef float  f32x4  __attribute__((ext_vector_type(4)));
typedef __bf16 bf16x8 __attribute__((ext_vector_type(8)));

// tanh(x) = (e^{2x}-1)/(e^{2x}+1), via hw exp2/rcp. Clamp keeps t finite.
__device__ __forceinline__ float fast_tanh(float x) {
    float xc = fminf(fmaxf(x, -9.0f), 9.0f);
    float t = __builtin_amdgcn_exp2f(xc * 2.885390081777927f); // 2*log2(e)
    return (t - 1.0f) * __builtin_amdgcn_rcpf(t + 1.0f);
}

// async global->LDS, 16B per lane, lane i writes ldst + i*16 (linear dest)
#define GLOAD16(gsrc, ldst) \
  __builtin_amdgcn_global_load_lds((const __attribute__((address_space(1))) void*)(gsrc), \
                                   (__attribute__((address_space(3))) void*)(ldst), 16, 0, 0)

// out[s,h,a] = (1/64) * sum_l tanh( sum_c x[s,c,l,a]*W[h,c] + bias[h] )
// Block = 4 waves, owns (s, 64-wide a chunk). x staged via global_load_lds
// (width 16) into LDS planes [c=32][a'=64], double-buffered over l-pairs,
// raw s_barrier + counted vmcnt so staging stays in flight across barriers.
// Bank-conflict fix: source-side XOR swizzle (a' = a ^ (w<<4), w = c>>3),
// inverse XOR on the read side -> 2 lanes/bank (free).
__global__ __launch_bounds__(256, 4) void tcrnn_kernel(
    const float* __restrict__ x,
    const float* __restrict__ Wih,
    const float* __restrict__ bih,
    const float* __restrict__ bhh,
    float* __restrict__ out)
{
    __shared__ float lds[2][2][NC * 64];   // [buf][l-plane][c*64 + a'] = 32 KiB

    const int tid   = threadIdx.x;
    const int lane  = tid & 63;
    const int w     = tid >> 6;          // wave 0..3
    const int bid   = blockIdx.x;        // 0..2047
    const int s     = bid >> 3;          // sample
    const int chunk = bid & 7;           // 8 chunks of 64 assets

    const int n     = lane & 15;         // a within tile / h-row for A frag
    const int g     = lane >> 4;         // k-group 0..3 (c = g*8 + j)

    // ---- A fragments: W[h][c], h = t*16 + n, k = g*8 + j ----
    bf16x8 Af[2];
    #pragma unroll
    for (int t = 0; t < 2; ++t) {
        const int h = t * 16 + n;
        const float4 w0 = *reinterpret_cast<const float4*>(Wih + h * NC + g * 8);
        const float4 w1 = *reinterpret_cast<const float4*>(Wih + h * NC + g * 8 + 4);
        Af[t][0] = (__bf16)w0.x; Af[t][1] = (__bf16)w0.y;
        Af[t][2] = (__bf16)w0.z; Af[t][3] = (__bf16)w0.w;
        Af[t][4] = (__bf16)w1.x; Af[t][5] = (__bf16)w1.y;
        Af[t][6] = (__bf16)w1.z; Af[t][7] = (__bf16)w1.w;
    }

    // ---- per-lane output bias: h_out = t*16 + g*4 + r ----
    float bias[8];
    #pragma unroll
    for (int t = 0; t < 2; ++t)
        #pragma unroll
        for (int r = 0; r < 4; ++r) {
            const int h = t * 16 + g * 4 + r;
            bias[t * 4 + r] = bih[h] + bhh[h];
        }

    // ---- staging addresses ----
    // Wave w DMA-stages rows c = w*8 + q*4 + (lane>>4); lane's 16B lands at
    // LDS a' = (lane&15)*4, so the GLOBAL source a is pre-swizzled by ^(w<<4).
    const int st_row = w * 8 + (lane >> 4);                        // + q*4
    const int a_st   = chunk * 64 + (((lane & 15) * 4) ^ (w << 4));
    const float* xst = x + (size_t)(s * NC + st_row) * (NL * NA) + a_st;

    // reader: lane wants x[c = g*8+j][a = w*16+n]; stored at a ^ (g<<4)
    const int swz_a = (w * 16 + n) ^ (g << 4);

    f32x4 acc0 = {0.f, 0.f, 0.f, 0.f};
    f32x4 acc1 = {0.f, 0.f, 0.f, 0.f};
    const f32x4 z = {0.f, 0.f, 0.f, 0.f};

    auto stage = [&](int r) {
        const int l0 = 2 * r;
        #pragma unroll
        for (int p = 0; p < 2; ++p)
            #pragma unroll
            for (int q = 0; q < 2; ++q) {
                const float* gsrc = xst + ((size_t)q * 4 * NL + l0 + p) * NA;
                float* ldst = &lds[r & 1][p][(w * 8 + q * 4) * 64];
                GLOAD16(gsrc, ldst);
            }
    };

    stage(0);
    for (int r = 0; r < 32; ++r) {
        if (r > 0) __builtin_amdgcn_s_barrier();     // readers of buf[(r+1)&1] done
        if (r < 31) {
            stage(r + 1);                            // 4 gload_lds into buf[(r+1)&1]
            asm volatile("s_waitcnt vmcnt(4)" ::: "memory");  // stage(r) complete
        } else {
            asm volatile("s_waitcnt vmcnt(0)" ::: "memory");
        }
        __builtin_amdgcn_s_barrier();                // stage(r) visible to all waves

        #pragma unroll
        for (int p = 0; p < 2; ++p) {
            const float* base = &lds[r & 1][p][g * 512 + swz_a];
            bf16x8 B;
            #pragma unroll
            for (int j = 0; j < 8; ++j)
                B[j] = (__bf16)base[j * 64];         // ds_read, 2-way banks (free)

            f32x4 pre0 = __builtin_amdgcn_mfma_f32_16x16x32_bf16(Af[0], B, z, 0, 0, 0);
            f32x4 pre1 = __builtin_amdgcn_mfma_f32_16x16x32_bf16(Af[1], B, z, 0, 0, 0);

            #pragma unroll
            for (int r4 = 0; r4 < 4; ++r4) {
                acc0[r4] += fast_tanh(pre0[r4] + bias[r4]);
                acc1[r4] += fast_tanh(pre1[r4] + bias[4 + r4]);
            }
        }
    }

    // ---- store: D col = n (=a), row = g*4 + r (+16 for tile 1) ----
    const int a = chunk * 64 + w * 16 + n;
    float* op = out + (size_t)s * (NH * NA) + a;
    #pragma unroll
    for (int r4 = 0; r4 < 4; ++r4) {
        op[(size_t)(g * 4 + r4) * NA]      = acc0[r4] * 0.015625f;
        op[(size_t)(16 + g * 4 + r4) * NA] = acc1[r4] * 0.015625f;
    }
}

extern "C" void kernel_launch(void* const* d_in, const int* in_sizes, int n_in,
                              void* d_out, int out_size, void* d_ws, size_t ws_size,
                              hipStream_t stream) {
    const float* x    = (const float*)d_in[0];
    const float* Wih  = (const float*)d_in[1];
    // d_in[2] = W_hh: mathematically dead (hx == 0 every step)
    const float* bih  = (const float*)d_in[3];
    const float* bhh  = (const float*)d_in[4];
    float* out = (float*)d_out;

    dim3 grid(NS * 8);   // 256 samples * 8 asset-chunks of 64
    dim3 block(256);
    tcrnn_kernel<<<grid, block, 0, stream>>>(x, Wih, bih, bhh, out);
}

// Round 3
// 213.140 us; speedup vs baseline: 1.1393x; 1.0099x over previous
//
#include <hip/hip_runtime.h>
#include <hip/hip_bf16.h>

// Problem dims (fixed by reference)
#define NS 256   // n_samples
#define NC 32    // n_channels (== K of the matvec)
#define NL 64    // lookback
#define NA 512   // n_assets
#define NH 32    // hidden

typedef float  f32x4  __attribute__((ext_vector_type(4)));
typedef __bf16 bf16x8 __attribute__((ext_vector_type(8)));

// tanh(x) = (e^{2x}-1)/(e^{2x}+1), via hw exp2/rcp. Clamp keeps t finite.
__device__ __forceinline__ float fast_tanh(float x) {
    float xc = fminf(fmaxf(x, -9.0f), 9.0f);
    float t = __builtin_amdgcn_exp2f(xc * 2.885390081777927f); // 2*log2(e)
    return (t - 1.0f) * __builtin_amdgcn_rcpf(t + 1.0f);
}

// async global->LDS, 16B per lane, lane i writes ldst + i*16 (linear dest)
#define GLOAD16(gsrc, ldst) \
  __builtin_amdgcn_global_load_lds((const __attribute__((address_space(1))) void*)(gsrc), \
                                   (__attribute__((address_space(3))) void*)(ldst), 16, 0, 0)

// out[s,h,a] = (1/64) * sum_l tanh( sum_c x[s,c,l,a]*W[h,c] + bias[h] )
// Block = 4 waves, owns (s, 64-wide a chunk).
// R3 changes vs R2:
//  * XCD-aware blockIdx swizzle: the 8 chunk-blocks of a sample co-locate on
//    one XCD (same L2) -> DRAM page locality for the 2KB (s,c,l) rows.
//  * 3-deep ring of l-pair buffers (48 KiB LDS), staged 2 iters ahead with
//    counted vmcnt(8) -> prefetch distance ~2 iters >> HBM latency.
__global__ __launch_bounds__(256, 4) void tcrnn_kernel(
    const float* __restrict__ x,
    const float* __restrict__ Wih,
    const float* __restrict__ bih,
    const float* __restrict__ bhh,
    float* __restrict__ out)
{
    __shared__ float lds[3][2][NC * 64];   // ring of 3 pair-buffers, 48 KiB

    const int tid   = threadIdx.x;
    const int lane  = tid & 63;
    const int w     = tid >> 6;          // wave 0..3

    // XCD swizzle: hw round-robins bid%8 across XCDs; give each XCD a
    // contiguous swz-range so all 8 chunks of a sample share one XCD/L2.
    const int swz   = ((blockIdx.x & 7) << 8) + (blockIdx.x >> 3);  // 2048%8==0: bijective
    const int s     = swz >> 3;          // sample
    const int chunk = swz & 7;           // 8 chunks of 64 assets

    const int n     = lane & 15;         // a within tile / h-row for A frag
    const int g     = lane >> 4;         // k-group 0..3 (c = g*8 + j)

    // ---- A fragments: W[h][c], h = t*16 + n, k = g*8 + j ----
    bf16x8 Af[2];
    #pragma unroll
    for (int t = 0; t < 2; ++t) {
        const int h = t * 16 + n;
        const float4 w0 = *reinterpret_cast<const float4*>(Wih + h * NC + g * 8);
        const float4 w1 = *reinterpret_cast<const float4*>(Wih + h * NC + g * 8 + 4);
        Af[t][0] = (__bf16)w0.x; Af[t][1] = (__bf16)w0.y;
        Af[t][2] = (__bf16)w0.z; Af[t][3] = (__bf16)w0.w;
        Af[t][4] = (__bf16)w1.x; Af[t][5] = (__bf16)w1.y;
        Af[t][6] = (__bf16)w1.z; Af[t][7] = (__bf16)w1.w;
    }

    // ---- per-lane output bias: h_out = t*16 + g*4 + r ----
    float bias[8];
    #pragma unroll
    for (int t = 0; t < 2; ++t)
        #pragma unroll
        for (int r = 0; r < 4; ++r) {
            const int h = t * 16 + g * 4 + r;
            bias[t * 4 + r] = bih[h] + bhh[h];
        }

    // ---- staging addresses ----
    // Wave w DMA-stages rows c = w*8 + q*4 + (lane>>4); lane's 16B lands at
    // LDS a' = (lane&15)*4, so the GLOBAL source a is pre-swizzled by ^(w<<4).
    const int st_row = w * 8 + (lane >> 4);                        // + q*4
    const int a_st   = chunk * 64 + (((lane & 15) * 4) ^ (w << 4));
    const float* xst = x + (size_t)(s * NC + st_row) * (NL * NA) + a_st;

    // reader: lane wants x[c = g*8+j][a = w*16+n]; stored at a ^ (g<<4)
    const int swz_a = (w * 16 + n) ^ (g << 4);

    f32x4 acc0 = {0.f, 0.f, 0.f, 0.f};
    f32x4 acc1 = {0.f, 0.f, 0.f, 0.f};
    const f32x4 z = {0.f, 0.f, 0.f, 0.f};

    auto stage = [&](int r, int buf) {   // 4 gload_lds: l-pair r into ring[buf]
        const int l0 = 2 * r;
        #pragma unroll
        for (int p = 0; p < 2; ++p)
            #pragma unroll
            for (int q = 0; q < 2; ++q) {
                const float* gsrc = xst + ((size_t)q * 4 * NL + l0 + p) * NA;
                float* ldst = &lds[buf][p][(w * 8 + q * 4) * 64];
                GLOAD16(gsrc, ldst);
            }
    };

    stage(0, 0);
    stage(1, 1);
    int bc = 0;                                   // compute buffer = r % 3
    for (int r = 0; r < 32; ++r) {
        // barrier #1: all waves done computing iter r-1 -> ring[(r+2)%3]
        // (read in iter r-1) is free for overwrite. Loads stay in flight.
        if (r > 0) asm volatile("s_barrier" ::: "memory");

        if (r + 2 < 32) {
            const int bs = (bc >= 1) ? bc - 1 : bc + 2;   // (r+2) % 3
            stage(r + 2, bs);
            asm volatile("s_waitcnt vmcnt(8)" ::: "memory");  // stage(r) done
        } else if (r + 1 < 32) {
            asm volatile("s_waitcnt vmcnt(4)" ::: "memory");
        } else {
            asm volatile("s_waitcnt vmcnt(0)" ::: "memory");
        }
        // barrier #2: stage(r) visible to all waves
        asm volatile("s_barrier" ::: "memory");

        #pragma unroll
        for (int p = 0; p < 2; ++p) {
            const float* base = &lds[bc][p][g * 512 + swz_a];
            bf16x8 B;
            #pragma unroll
            for (int j = 0; j < 8; ++j)
                B[j] = (__bf16)base[j * 64];      // ds_read, 2-way banks (free)

            f32x4 pre0 = __builtin_amdgcn_mfma_f32_16x16x32_bf16(Af[0], B, z, 0, 0, 0);
            f32x4 pre1 = __builtin_amdgcn_mfma_f32_16x16x32_bf16(Af[1], B, z, 0, 0, 0);

            #pragma unroll
            for (int r4 = 0; r4 < 4; ++r4) {
                acc0[r4] += fast_tanh(pre0[r4] + bias[r4]);
                acc1[r4] += fast_tanh(pre1[r4] + bias[4 + r4]);
            }
        }
        if (++bc == 3) bc = 0;
    }

    // ---- store: D col = n (=a), row = g*4 + r (+16 for tile 1) ----
    const int a = chunk * 64 + w * 16 + n;
    float* op = out + (size_t)s * (NH * NA) + a;
    #pragma unroll
    for (int r4 = 0; r4 < 4; ++r4) {
        op[(size_t)(g * 4 + r4) * NA]      = acc0[r4] * 0.015625f;
        op[(size_t)(16 + g * 4 + r4) * NA] = acc1[r4] * 0.015625f;
    }
}

extern "C" void kernel_launch(void* const* d_in, const int* in_sizes, int n_in,
                              void* d_out, int out_size, void* d_ws, size_t ws_size,
                              hipStream_t stream) {
    const float* x    = (const float*)d_in[0];
    const float* Wih  = (const float*)d_in[1];
    // d_in[2] = W_hh: mathematically dead (hx == 0 every step)
    const float* bih  = (const float*)d_in[3];
    const float* bhh  = (const float*)d_in[4];
    float* out = (float*)d_out;

    dim3 grid(NS * 8);   // 256 samples * 8 asset-chunks of 64
    dim3 block(256);
    tcrnn_kernel<<<grid, block, 0, stream>>>(x, Wih, bih, bhh, out);
}

// Round 4
// 212.420 us; speedup vs baseline: 1.1432x; 1.0034x over previous
//
#include <hip/hip_runtime.h>
#include <hip/hip_bf16.h>

// Problem dims (fixed by reference)
#define NS 256   // n_samples
#define NC 32    // n_channels (== K of the matvec)
#define NL 64    // lookback
#define NA 512   // n_assets
#define NH 32    // hidden

typedef float  f32x4  __attribute__((ext_vector_type(4)));
typedef __bf16 bf16x8 __attribute__((ext_vector_type(8)));

// tanh(x) = (e^{2x}-1)/(e^{2x}+1), via hw exp2/rcp. Clamp keeps t finite.
__device__ __forceinline__ float fast_tanh(float x) {
    float xc = fminf(fmaxf(x, -9.0f), 9.0f);
    float t = __builtin_amdgcn_exp2f(xc * 2.885390081777927f); // 2*log2(e)
    return (t - 1.0f) * __builtin_amdgcn_rcpf(t + 1.0f);
}

// async global->LDS, 16B per lane, lane i writes ldst + i*16 (linear dest)
#define GLOAD16(gsrc, ldst) \
  __builtin_amdgcn_global_load_lds((const __attribute__((address_space(1))) void*)(gsrc), \
                                   (__attribute__((address_space(3))) void*)(ldst), 16, 0, 0)

// out[s,h,a] = (1/64) * sum_l tanh( sum_c x[s,c,l,a]*W[h,c] + bias[h] )
// R4: widen block a-tile 64 -> 256 so each global_load_lds fetches ONE
// contiguous 1KB row segment (vs 4x 256B scattered) -> max DRAM bursts.
// Block = (s, 256-a half), 4 waves. Wave w stages c-rows 8w..8w+7 (one 1KB
// gload per row per l). LDS ring-2 of single-l planes [2][32][256]f32=64KiB,
// 2 blocks/CU. Counted vmcnt(8) keeps next-l loads in flight across barriers.
// Bank fix: both-sides XOR swizzle by ((c>>3)&1)<<4 -> 2 lanes/bank (free).
__global__ __launch_bounds__(256, 2) void tcrnn_kernel(
    const float* __restrict__ x,
    const float* __restrict__ Wih,
    const float* __restrict__ bih,
    const float* __restrict__ bhh,
    float* __restrict__ out)
{
    __shared__ float lds[2][NC][256];   // 64 KiB

    const int tid   = threadIdx.x;
    const int lane  = tid & 63;
    const int w     = tid >> 6;          // wave 0..3
    const int s     = blockIdx.x >> 1;   // sample
    const int chunk = blockIdx.x & 1;    // 2 halves of 256 assets

    const int n = lane & 15;             // a within MFMA tile / h-row for A
    const int g = lane >> 4;             // k-group 0..3 (c = g*8 + j)

    // ---- A fragments: W[h][c], h = t*16 + n, k = g*8 + j ----
    bf16x8 Af[2];
    #pragma unroll
    for (int t = 0; t < 2; ++t) {
        const int h = t * 16 + n;
        const float4 w0 = *reinterpret_cast<const float4*>(Wih + h * NC + g * 8);
        const float4 w1 = *reinterpret_cast<const float4*>(Wih + h * NC + g * 8 + 4);
        Af[t][0] = (__bf16)w0.x; Af[t][1] = (__bf16)w0.y;
        Af[t][2] = (__bf16)w0.z; Af[t][3] = (__bf16)w0.w;
        Af[t][4] = (__bf16)w1.x; Af[t][5] = (__bf16)w1.y;
        Af[t][6] = (__bf16)w1.z; Af[t][7] = (__bf16)w1.w;
    }

    // ---- per-lane output bias: h_out = t*16 + g*4 + r ----
    float bias[8];
    #pragma unroll
    for (int t = 0; t < 2; ++t)
        #pragma unroll
        for (int r = 0; r < 4; ++r) {
            const int h = t * 16 + g * 4 + r;
            bias[t * 4 + r] = bih[h] + bhh[h];
        }

    // ---- staging: wave w owns rows c = w*8 .. w*8+7 ----
    // LDS dest is linear (base + lane*16B); store position p gets global
    // a = p ^ Xw, so source lane offset is pre-swizzled. XOR bit is bit4
    // (16 floats = 64B): permutes 64B sub-blocks WITHIN the same 1KB line
    // range -> the instruction still covers one contiguous 1KB segment.
    const int Xw = (w & 1) << 4;
    const int lane_off = (lane * 4) ^ Xw;      // float offset within 256-chunk
    const float* xw = x + (size_t)(s * NC + w * 8) * (NL * NA)
                        + chunk * 256 + lane_off;

    auto stage = [&](int l, int buf) {         // 8x 1KB contiguous gloads
        #pragma unroll
        for (int i = 0; i < 8; ++i) {
            const float* gsrc = xw + ((size_t)i * NL + l) * NA;
            GLOAD16(gsrc, &lds[buf][w * 8 + i][0]);
        }
    };

    f32x4 acc[4][2];
    #pragma unroll
    for (int t2 = 0; t2 < 4; ++t2) {
        acc[t2][0] = (f32x4){0.f, 0.f, 0.f, 0.f};
        acc[t2][1] = (f32x4){0.f, 0.f, 0.f, 0.f};
    }
    const f32x4 z = {0.f, 0.f, 0.f, 0.f};
    const int Xg = (g & 1) << 4;               // reader-side inverse swizzle

    stage(0, 0);
    for (int l = 0; l < NL; ++l) {
        // barrier #1: all waves done computing l-1 -> buf[(l+1)&1] reusable
        if (l > 0) asm volatile("s_barrier" ::: "memory");

        if (l + 1 < NL) {
            stage(l + 1, (l + 1) & 1);                       // 8 gloads
            asm volatile("s_waitcnt vmcnt(8)" ::: "memory"); // stage(l) done
        } else {
            asm volatile("s_waitcnt vmcnt(0)" ::: "memory");
        }
        asm volatile("s_barrier" ::: "memory");  // stage(l) visible to all

        #pragma unroll
        for (int t2 = 0; t2 < 4; ++t2) {
            const int sa = (w * 64 + t2 * 16 + n) ^ Xg;
            const float* base = &lds[l & 1][g * 8][sa];
            bf16x8 B;
            #pragma unroll
            for (int j = 0; j < 8; ++j)
                B[j] = (__bf16)base[j * 256];    // 2-way banks (free)

            f32x4 pre0 = __builtin_amdgcn_mfma_f32_16x16x32_bf16(Af[0], B, z, 0, 0, 0);
            f32x4 pre1 = __builtin_amdgcn_mfma_f32_16x16x32_bf16(Af[1], B, z, 0, 0, 0);

            #pragma unroll
            for (int r4 = 0; r4 < 4; ++r4) {
                acc[t2][0][r4] += fast_tanh(pre0[r4] + bias[r4]);
                acc[t2][1][r4] += fast_tanh(pre1[r4] + bias[4 + r4]);
            }
        }
    }

    // ---- store: D col = n (=a), row = g*4 + r (+16 for tile 1) ----
    #pragma unroll
    for (int t2 = 0; t2 < 4; ++t2) {
        const int a = chunk * 256 + w * 64 + t2 * 16 + n;
        float* op = out + (size_t)s * (NH * NA) + a;
        #pragma unroll
        for (int r4 = 0; r4 < 4; ++r4) {
            op[(size_t)(g * 4 + r4) * NA]      = acc[t2][0][r4] * 0.015625f;
            op[(size_t)(16 + g * 4 + r4) * NA] = acc[t2][1][r4] * 0.015625f;
        }
    }
}

extern "C" void kernel_launch(void* const* d_in, const int* in_sizes, int n_in,
                              void* d_out, int out_size, void* d_ws, size_t ws_size,
                              hipStream_t stream) {
    const float* x    = (const float*)d_in[0];
    const float* Wih  = (const float*)d_in[1];
    // d_in[2] = W_hh: mathematically dead (hx == 0 every step)
    const float* bih  = (const float*)d_in[3];
    const float* bhh  = (const float*)d_in[4];
    float* out = (float*)d_out;

    dim3 grid(NS * 2);   // 256 samples * 2 asset-halves of 256
    dim3 block(256);
    tcrnn_kernel<<<grid, block, 0, stream>>>(x, Wih, bih, bhh, out);
}

// Round 5
// 186.901 us; speedup vs baseline: 1.2992x; 1.1365x over previous
//
#include <hip/hip_runtime.h>
#include <hip/hip_bf16.h>

// Problem dims (fixed by reference)
#define NS 256   // n_samples
#define NC 32    // n_channels (== K of the matvec)
#define NL 64    // lookback
#define NA 512   // n_assets
#define NH 32    // hidden

typedef float  f32x4  __attribute__((ext_vector_type(4)));
typedef __bf16 bf16x8 __attribute__((ext_vector_type(8)));

// tanh(x) = (e^{2x}-1)/(e^{2x}+1), via hw exp2/rcp. Clamp keeps t finite.
__device__ __forceinline__ float fast_tanh(float x) {
    float xc = fminf(fmaxf(x, -9.0f), 9.0f);
    float t = __builtin_amdgcn_exp2f(xc * 2.885390081777927f); // 2*log2(e)
    return (t - 1.0f) * __builtin_amdgcn_rcpf(t + 1.0f);
}

// async global->LDS, 16B per lane, lane i writes ldst + i*16 (linear dest)
#define GLOAD16(gsrc, ldst) \
  __builtin_amdgcn_global_load_lds((const __attribute__((address_space(1))) void*)(gsrc), \
                                   (__attribute__((address_space(3))) void*)(ldst), 16, 0, 0)

// out[s,h,a] = (1/64) * sum_l tanh( sum_c x[s,c,l,a]*W[h,c] + bias[h] )
// R5: DRAM stream-locality probe. Block = ONE full sample (a-tile 512):
//  * each (s,c,l) visit reads a full 2KB contiguous row (2 back-to-back
//    gload_lds) instead of 1KB halves from two different blocks;
//  * concurrent stream count halves: 256 blocks x 32 c-rows = 8192 (vs 16384);
//  * grid = 256 = exactly 1 block/CU; LDS ring-2 [2][32][512]f32 = 128 KiB
//    (dynamic LDS, opt-in via hipFuncSetAttribute).
// Same counted-vmcnt pipeline and both-sides XOR bank swizzle as R4.
__global__ __launch_bounds__(256, 1) void tcrnn_kernel(
    const float* __restrict__ x,
    const float* __restrict__ Wih,
    const float* __restrict__ bih,
    const float* __restrict__ bhh,
    float* __restrict__ out)
{
    extern __shared__ float lds[];       // [2][NC][512] = 128 KiB

    const int tid  = threadIdx.x;
    const int lane = tid & 63;
    const int w    = tid >> 6;           // wave 0..3
    const int s    = blockIdx.x;         // one sample per block

    const int n = lane & 15;             // a within MFMA tile / h-row for A
    const int g = lane >> 4;             // k-group 0..3 (c = g*8 + j)

    // ---- A fragments: W[h][c], h = t*16 + n, k = g*8 + j ----
    bf16x8 Af[2];
    #pragma unroll
    for (int t = 0; t < 2; ++t) {
        const int h = t * 16 + n;
        const float4 w0 = *reinterpret_cast<const float4*>(Wih + h * NC + g * 8);
        const float4 w1 = *reinterpret_cast<const float4*>(Wih + h * NC + g * 8 + 4);
        Af[t][0] = (__bf16)w0.x; Af[t][1] = (__bf16)w0.y;
        Af[t][2] = (__bf16)w0.z; Af[t][3] = (__bf16)w0.w;
        Af[t][4] = (__bf16)w1.x; Af[t][5] = (__bf16)w1.y;
        Af[t][6] = (__bf16)w1.z; Af[t][7] = (__bf16)w1.w;
    }

    // ---- per-lane output bias: h_out = t*16 + g*4 + r ----
    float bias[8];
    #pragma unroll
    for (int t = 0; t < 2; ++t)
        #pragma unroll
        for (int r = 0; r < 4; ++r) {
            const int h = t * 16 + g * 4 + r;
            bias[t * 4 + r] = bih[h] + bhh[h];
        }

    // ---- staging: wave w owns c-rows 8w..8w+7; 2KB contiguous per row ----
    // LDS dest linear (base + lane*16B); source lane offset pre-swizzled by
    // Xw (bit4 = 64B blocks) so stored a' = a ^ Xw_row within each 256-half.
    const int Xw = (w & 1) << 4;
    const int lane_off = (lane * 4) ^ Xw;        // float offset within half
    const float* xw = x + (size_t)(s * NC + w * 8) * (NL * NA) + lane_off;

    auto stage = [&](int l, int buf) {           // 16 gloads: 8 rows x 2KB
        #pragma unroll
        for (int i = 0; i < 8; ++i) {
            const float* gsrc = xw + ((size_t)i * NL + l) * NA;
            float* ldst = lds + (((size_t)buf * NC + w * 8 + i) << 9);
            GLOAD16(gsrc, ldst);                 // a 0..255   (swizzled)
            GLOAD16(gsrc + 256, ldst + 256);     // a 256..511 (swizzled)
        }
    };

    f32x4 acc[8][2];
    #pragma unroll
    for (int t2 = 0; t2 < 8; ++t2) {
        acc[t2][0] = (f32x4){0.f, 0.f, 0.f, 0.f};
        acc[t2][1] = (f32x4){0.f, 0.f, 0.f, 0.f};
    }
    const f32x4 z = {0.f, 0.f, 0.f, 0.f};
    const int Xg = (g & 1) << 4;                 // reader-side inverse swizzle

    stage(0, 0);
    for (int l = 0; l < NL; ++l) {
        // barrier #1: all waves done computing l-1 -> buf[(l+1)&1] reusable.
        if (l > 0) asm volatile("s_barrier" ::: "memory");

        if (l + 1 < NL) {
            stage(l + 1, (l + 1) & 1);                        // 16 gloads
            asm volatile("s_waitcnt vmcnt(16)" ::: "memory"); // stage(l) done
        } else {
            asm volatile("s_waitcnt vmcnt(0)" ::: "memory");
        }
        asm volatile("s_barrier" ::: "memory");   // stage(l) visible to all

        // wave w computes a-slice [w*128, w*128+128)
        #pragma unroll
        for (int t2 = 0; t2 < 8; ++t2) {
            const int A    = w * 128 + t2 * 16 + n;          // global a
            const int half = A >> 8;                          // 0 or 1
            const int sa   = half * 256 + ((A & 255) ^ Xg);   // swizzled pos
            const float* base = lds + (((size_t)(l & 1) * NC + g * 8) << 9) + sa;
            bf16x8 B;
            #pragma unroll
            for (int j = 0; j < 8; ++j)
                B[j] = (__bf16)base[j * 512];     // 2-way banks (free)

            f32x4 pre0 = __builtin_amdgcn_mfma_f32_16x16x32_bf16(Af[0], B, z, 0, 0, 0);
            f32x4 pre1 = __builtin_amdgcn_mfma_f32_16x16x32_bf16(Af[1], B, z, 0, 0, 0);

            #pragma unroll
            for (int r4 = 0; r4 < 4; ++r4) {
                acc[t2][0][r4] += fast_tanh(pre0[r4] + bias[r4]);
                acc[t2][1][r4] += fast_tanh(pre1[r4] + bias[4 + r4]);
            }
        }
    }

    // ---- store: D col = n (=a), row = g*4 + r (+16 for tile 1) ----
    #pragma unroll
    for (int t2 = 0; t2 < 8; ++t2) {
        const int a = w * 128 + t2 * 16 + n;
        float* op = out + (size_t)s * (NH * NA) + a;
        #pragma unroll
        for (int r4 = 0; r4 < 4; ++r4) {
            op[(size_t)(g * 4 + r4) * NA]      = acc[t2][0][r4] * 0.015625f;
            op[(size_t)(16 + g * 4 + r4) * NA] = acc[t2][1][r4] * 0.015625f;
        }
    }
}

extern "C" void kernel_launch(void* const* d_in, const int* in_sizes, int n_in,
                              void* d_out, int out_size, void* d_ws, size_t ws_size,
                              hipStream_t stream) {
    const float* x    = (const float*)d_in[0];
    const float* Wih  = (const float*)d_in[1];
    // d_in[2] = W_hh: mathematically dead (hx == 0 every step)
    const float* bih  = (const float*)d_in[3];
    const float* bhh  = (const float*)d_in[4];
    float* out = (float*)d_out;

    // 128 KiB dynamic LDS needs explicit opt-in (gfx950 has 160 KiB/CU).
    // Idempotent, not a stream op -> graph-capture safe.
    (void)hipFuncSetAttribute((const void*)tcrnn_kernel,
                              hipFuncAttributeMaxDynamicSharedMemorySize,
                              2 * NC * NA * (int)sizeof(float));

    dim3 grid(NS);      // one block per sample, 1 block/CU
    dim3 block(256);    // 4 waves
    tcrnn_kernel<<<grid, block, 2 * NC * NA * sizeof(float), stream>>>(
        x, Wih, bih, bhh, out);
}